// Round 14
// baseline (197.555 us; speedup 1.0000x reference)
//
#include <hip/hip_runtime.h>

#define B_   2
#define H_   16
#define G_   4
#define S_   2048
#define D_   128
#define I_   2048

#define BM   256
#define BN   64
#define TPB  512   // 8 waves x 32 q-rows
#define NIT  (I_ / BN)   // 32
#define TSZ  8192        // one tile: 16 KB = 8192 f16 (K/U: 64x128, Vt: 128x64)

// K/U swizzle: XOR 8-elem (16B) granule index with (row&15) — a K/U row has 16
// granules, so 16-lane quarter-waves hit 16 DISTINCT granules (max 2-way = free).
// (row&7 left 4-way conflicts: rows r/r+8 alias; measured 1.26e7 in R13.)
// Vt rows have only 8 granules -> keep (d&7), already <=2-way.
// The ws image is PRE-swizzled by the convert kernel; DMA is linear; reads swizzle.
#define KIDX(r,c) ((r)*128 + ((c) ^ (((r)&15)<<3)))  // Ks/Us: [64][128] f16
#define VIDX(d,c) ((d)*64  + ((c) ^ (((d)&7)<<3)))   // Vt:    [128][64] f16

static constexpr float SCALE = 0.08838834764831845f;  // 1/sqrt(128)

typedef __fp16   p2v  __attribute__((ext_vector_type(2)));
typedef _Float16 h8v  __attribute__((ext_vector_type(8)));
typedef float    f4v  __attribute__((ext_vector_type(4)));
typedef float    f16v __attribute__((ext_vector_type(16)));
typedef int      i4v  __attribute__((ext_vector_type(4)));

__device__ __forceinline__ int pkf16(float a, float b) {
    p2v t = __builtin_amdgcn_cvt_pkrtz(a, b);
    int r; __builtin_memcpy(&r, &t, 4); return r;
}

// async global->LDS, 16 B per lane; LDS dest = wave-uniform base + lane*16
#define GL_LDS(gp, lp) __builtin_amdgcn_global_load_lds(                      \
    (const __attribute__((address_space(1))) void*)(gp),                      \
    (__attribute__((address_space(3))) void*)(lp), 16, 0, 0)

// ---------------- pre-pass: K/U/V f32 -> f16 tiles, transposed (V) + pre-swizzled
// ws layout: [kh][m][it][8192 f16], m: 0=K, 1=U, 2=Vt
__global__ __launch_bounds__(256) void convert_kernel(
    const float* __restrict__ Kg, const float* __restrict__ Ug,
    const float* __restrict__ Vg, _Float16* __restrict__ ws)
{
    const int bid = blockIdx.x;
    const int tid = threadIdx.x;
    __shared__ float vt[64 * 128];
    if (bid < 256) {
        // K/U tile: image[r*128+cc] = src[it*64+r][cc ^ ((r&15)<<3)]
        const int kh = bid >> 6, m = (bid >> 5) & 1, it = bid & 31;
        const float* src = (m ? Ug : Kg) + (size_t)kh * I_ * D_ + (size_t)it * BN * D_;
        _Float16* dst = ws + (((size_t)kh * 3 + m) * 32 + it) * TSZ;
        const int r   = tid >> 2;
        const int cb  = (tid & 3) * 32;
        const int swz = (r & 15) << 3;
#pragma unroll
        for (int g = 0; g < 4; ++g) {
            const int cc0 = cb + g * 8;
            const int d0  = cc0 ^ swz;
            const float4 a = *(const float4*)(src + r * D_ + d0);
            const float4 c = *(const float4*)(src + r * D_ + d0 + 4);
            h8v v; p2v* v2 = (p2v*)&v;
            v2[0] = __builtin_amdgcn_cvt_pkrtz(a.x, a.y);
            v2[1] = __builtin_amdgcn_cvt_pkrtz(a.z, a.w);
            v2[2] = __builtin_amdgcn_cvt_pkrtz(c.x, c.y);
            v2[3] = __builtin_amdgcn_cvt_pkrtz(c.z, c.w);
            *(h8v*)(dst + r * 128 + cc0) = v;
        }
    } else {
        // Vt tile: image[d*64+cc] = V[it*64 + (cc ^ ((d&7)<<3))][d], via LDS transpose
        const int v  = bid - 256;
        const int kh = v >> 5, it = v & 31;
        const float* src = Vg + (size_t)kh * I_ * D_ + (size_t)it * BN * D_;
#pragma unroll
        for (int p = 0; p < 8; ++p) {
            const int idx = p * 256 + tid;
            const int i   = idx >> 5;
            const int d4  = (idx & 31) * 4;
            *(float4*)(&vt[i * 128 + d4]) = *(const float4*)(src + (size_t)i * D_ + d4);
        }
        __syncthreads();
        _Float16* dst = ws + (((size_t)kh * 3 + 2) * 32 + it) * TSZ;
        const int d   = tid >> 1;
        const int cb  = (tid & 1) * 32;
        const int swz = (d & 7) << 3;
#pragma unroll
        for (int g = 0; g < 4; ++g) {
            const int cc0 = cb + g * 8;
            const int ib  = cc0 ^ swz;   // 8 consecutive i
            h8v w; p2v* w2 = (p2v*)&w;
#pragma unroll
            for (int pr = 0; pr < 4; ++pr)
                w2[pr] = __builtin_amdgcn_cvt_pkrtz(vt[(ib + 2 * pr) * 128 + d],
                                                    vt[(ib + 2 * pr + 1) * 128 + d]);
            *(h8v*)(dst + d * 64 + cc0) = w;
        }
    }
}

// ---------------- main kernel
__global__ __launch_bounds__(TPB, 2) void flashmlp_kernel(
    const float* __restrict__ Qg, const _Float16* __restrict__ ws,
    float* __restrict__ Og)
{
    // LDS: dbuf K/U/V = 6 x 16 KB = 96 KB (1 block/CU)
    __shared__ _Float16 Ks[2 * TSZ];
    __shared__ _Float16 Us[2 * TSZ];
    __shared__ _Float16 Vt[2 * TSZ];

    // ---- block decode with XCD swizzle: xcd = bid&7 -> kv-head = xcd>>1
    const int bid   = blockIdx.x;
    const int xcd   = bid & 7;
    const int kh    = xcd >> 1;
    const int j     = ((bid >> 3) << 1) | (xcd & 1);   // 0..63 within head
    const int stile = j & 7;
    const int bg    = j >> 3;
    const int b     = bg >> 2;
    const int g     = bg & 3;
    const int h     = kh * G_ + g;

    const int tid  = threadIdx.x;
    const int wave = tid >> 6;         // 0..7
    const int lane = tid & 63;
    const int l31  = lane & 31;
    const int hl   = lane >> 5;

    const size_t qbase = ((size_t)(b * H_ + h) * S_ + (size_t)stile * BM) * D_;
    const _Float16* wsK = ws + (size_t)kh * 3 * 32 * TSZ;            // K tiles
    const _Float16* wsU = wsK + (size_t)32 * TSZ;                    // U tiles
    const _Float16* wsV = wsK + (size_t)64 * TSZ;                    // Vt tiles

    // per-lane source elem offset within a tile (wave covers 2 KB; 2 calls of 1 KB)
    const int so = wave * 1024 + lane * 8;
    const int su = wave * 1024;        // wave-uniform LDS elem offset

    // ---- Q fragments as the 32x32x16 B-operand (SCALE folded in)
    h8v qf[8];
    {
        const float* qp = Qg + qbase + (size_t)(wave * 32 + l31) * D_;
#pragma unroll
        for (int ks = 0; ks < 8; ++ks) {
            const float4 a = *(const float4*)(qp + ks * 16 + hl * 8);
            const float4 c = *(const float4*)(qp + ks * 16 + hl * 8 + 4);
            h8v v; p2v* v2 = (p2v*)&v;
            v2[0] = __builtin_amdgcn_cvt_pkrtz(a.x * SCALE, a.y * SCALE);
            v2[1] = __builtin_amdgcn_cvt_pkrtz(a.z * SCALE, a.w * SCALE);
            v2[2] = __builtin_amdgcn_cvt_pkrtz(c.x * SCALE, c.y * SCALE);
            v2[3] = __builtin_amdgcn_cvt_pkrtz(c.z * SCALE, c.w * SCALE);
            qf[ks] = v;
        }
    }

    // acc_o[dt]: O^T (32d x 32q); lane col q=l31, row d = dt*32+(reg&3)+8*(reg>>2)+4*hl
    f16v acc_o[4];
#pragma unroll
    for (int dt = 0; dt < 4; ++dt)
#pragma unroll
        for (int e = 0; e < 16; ++e)
            acc_o[dt][e] = 0.f;

    // ---- prologue: DMA tile 0 into buf 0 (syncthreads drains vmcnt)
    {
        GL_LDS(wsK + so,       Ks + su);
        GL_LDS(wsK + so + 512, Ks + su + 512);
        GL_LDS(wsU + so,       Us + su);
        GL_LDS(wsU + so + 512, Us + su + 512);
        GL_LDS(wsV + so,       Vt + su);
        GL_LDS(wsV + so + 512, Vt + su + 512);
    }
    __syncthreads();

    for (int it = 0; it < NIT; ++it) {
        const int cur = it & 1;
        const _Float16* ksb = Ks + cur * TSZ;
        const _Float16* usb = Us + cur * TSZ;
        const _Float16* vtb = Vt + cur * TSZ;

        // ---- 1) DMA tile t+1 into buf[cur^1]; completes by the end-of-iter barrier
        if (it + 1 < NIT) {
            const int nb = (cur ^ 1) * TSZ;
            const _Float16* kt = wsK + (size_t)(it + 1) * TSZ;
            const _Float16* ut = wsU + (size_t)(it + 1) * TSZ;
            const _Float16* vt = wsV + (size_t)(it + 1) * TSZ;
            GL_LDS(kt + so,       Ks + nb + su);
            GL_LDS(kt + so + 512, Ks + nb + su + 512);
            GL_LDS(ut + so,       Us + nb + su);
            GL_LDS(ut + so + 512, Us + nb + su + 512);
            GL_LDS(vt + so,       Vt + nb + su);
            GL_LDS(vt + so + 512, Vt + nb + su + 512);
        }

        // ---- 2) per 32-i half: swapped QK (32x32x16), gate+pack in-register,
        // then PV for that half (overlaps next half's QK LDS reads)
#pragma unroll
        for (int t2 = 0; t2 < 2; ++t2) {
            f16v am, an;
#pragma unroll
            for (int e = 0; e < 16; ++e) { am[e] = 0.f; an[e] = 0.f; }
            __builtin_amdgcn_s_setprio(1);
#pragma unroll
            for (int ks = 0; ks < 8; ++ks) {
                const h8v kf = *(const h8v*)(&ksb[KIDX(t2 * 32 + l31, ks * 16 + hl * 8)]);
                const h8v uf = *(const h8v*)(&usb[KIDX(t2 * 32 + l31, ks * 16 + hl * 8)]);
                am = __builtin_amdgcn_mfma_f32_32x32x16_f16(kf, qf[ks], am, 0, 0, 0);
                an = __builtin_amdgcn_mfma_f32_32x32x16_f16(uf, qf[ks], an, 0, 0, 0);
            }
            __builtin_amdgcn_s_setprio(0);

            // gate: A = silu(M) * N; reg r -> i = (r&3)+8*(r>>2)+4*hl
            int P[8];
#pragma unroll
            for (int p = 0; p < 8; ++p) {
                const float m0 = am[2 * p + 0], n0 = an[2 * p + 0];
                const float m1 = am[2 * p + 1], n1 = an[2 * p + 1];
                const float g0 = m0 * __builtin_amdgcn_rcpf(1.f + __expf(-m0)) * n0;
                const float g1 = m1 * __builtin_amdgcn_rcpf(1.f + __expf(-m1)) * n1;
                P[p] = pkf16(g0, g1);
            }
            // redistribute lane halves -> PV B-frags (k = hl*8+j)
            auto sA = __builtin_amdgcn_permlane32_swap(P[0], P[2], false, false);
            auto sB = __builtin_amdgcn_permlane32_swap(P[1], P[3], false, false);
            auto sC = __builtin_amdgcn_permlane32_swap(P[4], P[6], false, false);
            auto sD = __builtin_amdgcn_permlane32_swap(P[5], P[7], false, false);
            h8v pb0, pb1;
            {
                i4v wlo = i4v{static_cast<int>(sA[0]), static_cast<int>(sB[0]),
                              static_cast<int>(sA[1]), static_cast<int>(sB[1])};
                i4v whi = i4v{static_cast<int>(sC[0]), static_cast<int>(sD[0]),
                              static_cast<int>(sC[1]), static_cast<int>(sD[1])};
                __builtin_memcpy(&pb0, &wlo, 16);
                __builtin_memcpy(&pb1, &whi, 16);
            }

            // PV for this 32-i half: ks2 = t2*2 + {0,1}
#pragma unroll
            for (int k2 = 0; k2 < 2; ++k2) {
                const int ks2 = t2 * 2 + k2;
                const h8v pb = k2 ? pb1 : pb0;
                h8v va[4];
#pragma unroll
                for (int dt = 0; dt < 4; ++dt)
                    va[dt] = *(const h8v*)(&vtb[VIDX(dt * 32 + l31, ks2 * 16 + hl * 8)]);
                __builtin_amdgcn_s_setprio(1);
#pragma unroll
                for (int dt = 0; dt < 4; ++dt)
                    acc_o[dt] = __builtin_amdgcn_mfma_f32_32x32x16_f16(va[dt], pb, acc_o[dt], 0, 0, 0);
                __builtin_amdgcn_s_setprio(0);
            }
        }

        // ---- 3) single barrier: DMA drained (vmcnt) + buf[cur] reads done
        __syncthreads();
    }

    // ---- epilogue: lane owns one q-row; d = dt*32 + g4*8 + hl*4 + (0..3)
    {
        const int qrow = stile * BM + wave * 32 + l31;
        float* op = Og + ((size_t)(b * H_ + h) * S_ + qrow) * D_;
#pragma unroll
        for (int dt = 0; dt < 4; ++dt)
#pragma unroll
            for (int g4 = 0; g4 < 4; ++g4) {
                f4v v = f4v{acc_o[dt][4 * g4 + 0], acc_o[dt][4 * g4 + 1],
                            acc_o[dt][4 * g4 + 2], acc_o[dt][4 * g4 + 3]};
                *(f4v*)(op + dt * 32 + g4 * 8 + hl * 4) = v;
            }
    }
}

extern "C" void kernel_launch(void* const* d_in, const int* in_sizes, int n_in,
                              void* d_out, int out_size, void* d_ws, size_t ws_size,
                              hipStream_t stream) {
    const float* Q = (const float*)d_in[0];
    const float* K = (const float*)d_in[1];
    const float* U = (const float*)d_in[2];
    const float* V = (const float*)d_in[3];
    float* out = (float*)d_out;
    _Float16* ws = (_Float16*)d_ws;   // needs 4*3*32*16384 B = 6.3 MB

    convert_kernel<<<dim3(384), dim3(256), 0, stream>>>(K, U, V, ws);
    flashmlp_kernel<<<dim3((S_ / BM) * B_ * H_), dim3(TPB), 0, stream>>>(Q, ws, out);
}